// Round 6
// baseline (119.893 us; speedup 1.0000x reference)
//
#include <hip/hip_runtime.h>
#include <hip/hip_bf16.h>

#define BATCH 16
#define NNODE 2048
#define NEDGE 65536
#define DIN   256
#define DOUT  256
#define KDIM  512   // 2*DIN

typedef __attribute__((ext_vector_type(8))) short short8;
typedef __attribute__((ext_vector_type(8))) ushort ushort8;
typedef __attribute__((ext_vector_type(4))) float f32x4;

__device__ __forceinline__ ushort f2bf(float f) {
    union { float f; unsigned u; } v; v.f = f;
    unsigned u = v.u;
    unsigned r = (u + 0x7fffu + ((u >> 16) & 1u)) >> 16;  // RNE
    return (ushort)r;
}
__device__ __forceinline__ float bf2f(ushort h) {
    union { unsigned u; float f; } v; v.u = ((unsigned)h) << 16;
    return v.f;
}

#define ASYNC_COPY16(gsrc, ldst) \
    __builtin_amdgcn_global_load_lds((const __attribute__((address_space(1))) void*)(gsrc), \
                                     (__attribute__((address_space(3))) void*)(ldst), 16, 0, 0)

// ---------------------------------------------------------------------------
// Fused prep + full CSR build (1056 blocks x 1024 threads):
//   blocks [0,16):      one block per batch: LDS histogram of dst ->
//                       LDS scan -> LDS-cursor counting-sort fill of srcIdx.
//                       counts + start-offsets written to global. No global
//                       atomics anywhere; srcIdx region is CU/XCD-local.
//   blocks [16,1040):   convert X fp32->bf16 (8 elems/thread)
//   blocks [1040,1056): convert W fp32->bf16
// ---------------------------------------------------------------------------
__global__ __launch_bounds__(1024) void prep_csr_kernel(
        const float* __restrict__ X, const float* __restrict__ W,
        const int* __restrict__ E,
        int* __restrict__ counts, int* __restrict__ cursor,
        int* __restrict__ srcIdx,
        ushort* __restrict__ Xbf, ushort* __restrict__ Wbf) {
    int bid = blockIdx.x;
    int t = threadIdx.x;
    if (bid < 16) {
        __shared__ int hist[NNODE];     // histogram, then reused as cursor
        __shared__ int tsum[1024];
        int b = bid;
        hist[t] = 0;
        hist[t + 1024] = 0;
        __syncthreads();
        const int4* srcs = reinterpret_cast<const int4*>(E + (size_t)b * 2 * NEDGE);
        const int4* dsts = reinterpret_cast<const int4*>(E + (size_t)b * 2 * NEDGE + NEDGE);
        // pass 1: histogram (LDS atomics)
#pragma unroll
        for (int j = 0; j < 16; ++j) {
            int4 d = dsts[j * 1024 + t];
            atomicAdd(&hist[d.x], 1);
            atomicAdd(&hist[d.y], 1);
            atomicAdd(&hist[d.z], 1);
            atomicAdd(&hist[d.w], 1);
        }
        __syncthreads();
        int c0 = hist[2 * t], c1 = hist[2 * t + 1];
        tsum[t] = c0 + c1;
        __syncthreads();
        for (int off = 1; off < 1024; off <<= 1) {
            int v = (t >= off) ? tsum[t - off] : 0;
            __syncthreads();
            tsum[t] += v;
            __syncthreads();
        }
        int run = (t == 0) ? 0 : tsum[t - 1];
        int base = b * NNODE;
        counts[base + 2 * t]     = c0;
        counts[base + 2 * t + 1] = c1;
        cursor[base + 2 * t]     = run;        // global = start offsets
        cursor[base + 2 * t + 1] = run + c0;
        __syncthreads();                        // all c0/c1 reads done
        hist[2 * t]     = run;                  // LDS cursor for fill
        hist[2 * t + 1] = run + c0;
        __syncthreads();
        // pass 2: counting-sort fill via LDS cursor
        int* sb = srcIdx + (size_t)b * NEDGE;
#pragma unroll
        for (int j = 0; j < 16; ++j) {
            int4 s = srcs[j * 1024 + t];
            int4 d = dsts[j * 1024 + t];
            sb[atomicAdd(&hist[d.x], 1)] = s.x;
            sb[atomicAdd(&hist[d.y], 1)] = s.y;
            sb[atomicAdd(&hist[d.z], 1)] = s.z;
            sb[atomicAdd(&hist[d.w], 1)] = s.w;
        }
    } else if (bid < 1040) {
        size_t i = (size_t)(bid - 16) * 1024 + t;
        const float4* p = reinterpret_cast<const float4*>(X + i * 8);
        float4 u = p[0], v = p[1];
        ushort4 o0 = { f2bf(u.x), f2bf(u.y), f2bf(u.z), f2bf(u.w) };
        ushort4 o1 = { f2bf(v.x), f2bf(v.y), f2bf(v.z), f2bf(v.w) };
        *reinterpret_cast<ushort4*>(Xbf + i * 8)     = o0;
        *reinterpret_cast<ushort4*>(Xbf + i * 8 + 4) = o1;
    } else {
        size_t i = (size_t)(bid - 1040) * 1024 + t;
        const float4* p = reinterpret_cast<const float4*>(W + i * 8);
        float4 u = p[0], v = p[1];
        ushort4 o0 = { f2bf(u.x), f2bf(u.y), f2bf(u.z), f2bf(u.w) };
        ushort4 o1 = { f2bf(v.x), f2bf(v.y), f2bf(v.z), f2bf(v.w) };
        *reinterpret_cast<ushort4*>(Wbf + i * 8)     = o0;
        *reinterpret_cast<ushort4*>(Wbf + i * 8 + 4) = o1;
    }
}

// ---------------------------------------------------------------------------
// pull-style neighbor mean, bf16 features, fp32 accumulate. One wave per
// node; half-wave per edge; lane owns 8 features (16B loads); 16-edge unroll
// -> 8 independent gathers in flight. XCD swizzle: 2 batches per XCD.
// cursor holds START offsets (from prep_csr).
// ---------------------------------------------------------------------------
__global__ __launch_bounds__(256) void aggregate_kernel(
        const ushort* __restrict__ Xbf,
        const int* __restrict__ srcIdx,
        const int* __restrict__ cursor,
        const int* __restrict__ counts,
        ushort* __restrict__ Gbf) {
    int bid = blockIdx.x;                     // 8192 blocks
    int blk = (bid & 7) * 1024 + (bid >> 3);  // XCD-contiguous remap (bijective)
    int wave = threadIdx.x >> 6;
    int lane = threadIdx.x & 63;
    int half = lane >> 5;                     // 0: even edges, 1: odd edges
    int f0 = (lane & 31) * 8;                 // 8 features per lane
    int node = blk * 4 + wave;                // 0 .. B*N-1
    int b = node >> 11;
    int deg = counts[node];
    int start = cursor[node];
    const ushort* xb = Xbf + (size_t)b * NNODE * DIN;
    const int* sidx = srcIdx + (size_t)b * NEDGE + start;

    float acc[8] = {};
    int i = 0;
    for (; i + 16 <= deg; i += 16) {
        int s[8];
#pragma unroll
        for (int u = 0; u < 8; ++u) s[u] = sidx[i + 2 * u + half];
        ushort8 v[8];
#pragma unroll
        for (int u = 0; u < 8; ++u)
            v[u] = *reinterpret_cast<const ushort8*>(xb + (size_t)s[u] * DIN + f0);
#pragma unroll
        for (int u = 0; u < 8; ++u)
#pragma unroll
            for (int j = 0; j < 8; ++j) acc[j] += bf2f(v[u][j]);
    }
    for (; i + 8 <= deg; i += 8) {
        int s0 = sidx[i + 0 + half], s1 = sidx[i + 2 + half];
        int s2 = sidx[i + 4 + half], s3 = sidx[i + 6 + half];
        ushort8 v0 = *reinterpret_cast<const ushort8*>(xb + (size_t)s0 * DIN + f0);
        ushort8 v1 = *reinterpret_cast<const ushort8*>(xb + (size_t)s1 * DIN + f0);
        ushort8 v2 = *reinterpret_cast<const ushort8*>(xb + (size_t)s2 * DIN + f0);
        ushort8 v3 = *reinterpret_cast<const ushort8*>(xb + (size_t)s3 * DIN + f0);
#pragma unroll
        for (int j = 0; j < 8; ++j)
            acc[j] += (bf2f(v0[j]) + bf2f(v1[j])) + (bf2f(v2[j]) + bf2f(v3[j]));
    }
    for (; i + 2 <= deg; i += 2) {
        int s0 = sidx[i + half];
        ushort8 v0 = *reinterpret_cast<const ushort8*>(xb + (size_t)s0 * DIN + f0);
#pragma unroll
        for (int j = 0; j < 8; ++j) acc[j] += bf2f(v0[j]);
    }
    if (i < deg && half == 0) {
        int s0 = sidx[i];
        ushort8 v0 = *reinterpret_cast<const ushort8*>(xb + (size_t)s0 * DIN + f0);
#pragma unroll
        for (int j = 0; j < 8; ++j) acc[j] += bf2f(v0[j]);
    }
#pragma unroll
    for (int j = 0; j < 8; ++j) acc[j] += __shfl_xor(acc[j], 32, 64);

    if (half == 0) {
        float sc = 1.0f / (float)max(deg, 1);
        ushort8 o;
#pragma unroll
        for (int j = 0; j < 8; ++j) o[j] = f2bf(acc[j] * sc);
        *reinterpret_cast<ushort8*>(Gbf + (size_t)node * DIN + f0) = o;
    }
}

// ---------------------------------------------------------------------------
// bf16 MFMA GEMM, 128x128 tile, BK=32, double-buffered LDS, 2-phase pipeline
// (counted vmcnt, raw s_barrier). XCD-chunked swizzle.
// ---------------------------------------------------------------------------
__global__ __launch_bounds__(256) void gemm_kernel(
        const ushort* __restrict__ Xbf,
        const ushort* __restrict__ Gbf,
        const ushort* __restrict__ Wbf,
        const float* __restrict__ bias,
        float* __restrict__ out) {
    __shared__ ushort As[2][128 * 32];   // [buf][row*32 + k]
    __shared__ ushort Bs[2][128 * 32];
    const int tid = threadIdx.x;
    const int wid = tid >> 6, lane = tid & 63;

    int orig = blockIdx.x;
    int logical = (orig & 7) * 64 + (orig >> 3);
    int bx = logical >> 1;
    int by = logical & 1;
    const int rowBase = bx * 128;
    const int colBase = by * 128;
    const int wm = wid >> 1, wn = wid & 1;

    f32x4 acc[4][4] = {};

    const int lr = lane >> 2;
    const int lk = (lane & 3) * 8;

    const ushort* Arow = Xbf + (size_t)rowBase * DIN;
    const ushort* Grow = Gbf + (size_t)rowBase * DIN;
    const ushort* Brow = Wbf + (size_t)colBase * KDIM;
    const int r0 = wid * 16 + lr;

#define STAGE(k0, buf) do {                                                   \
        const ushort* Ab = ((k0) < DIN) ? (Arow + (k0)) : (Grow + ((k0) - DIN)); \
        const ushort* Bb = Brow + (k0);                                       \
        ASYNC_COPY16(Ab + (size_t)r0 * DIN + lk,          &As[buf][wid * 512]);       \
        ASYNC_COPY16(Ab + (size_t)(r0 + 64) * DIN + lk,   &As[buf][2048 + wid * 512]);\
        ASYNC_COPY16(Bb + (size_t)r0 * KDIM + lk,         &Bs[buf][wid * 512]);       \
        ASYNC_COPY16(Bb + (size_t)(r0 + 64) * KDIM + lk,  &Bs[buf][2048 + wid * 512]);\
    } while (0)

    STAGE(0, 0);
    int cur = 0;
    for (int t = 0; t < 16; ++t) {
        if (t < 15) {
            STAGE((t + 1) * 32, cur ^ 1);
            asm volatile("s_waitcnt vmcnt(4)" ::: "memory");
        } else {
            asm volatile("s_waitcnt vmcnt(0)" ::: "memory");
        }
        __builtin_amdgcn_s_barrier();

        short8 a[4], b[4];
#pragma unroll
        for (int m = 0; m < 4; ++m)
            a[m] = *reinterpret_cast<const short8*>(
                &As[cur][(wm * 64 + m * 16 + (lane & 15)) * 32 + (lane >> 4) * 8]);
#pragma unroll
        for (int n = 0; n < 4; ++n)
            b[n] = *reinterpret_cast<const short8*>(
                &Bs[cur][(wn * 64 + n * 16 + (lane & 15)) * 32 + (lane >> 4) * 8]);
#pragma unroll
        for (int m = 0; m < 4; ++m)
#pragma unroll
            for (int n = 0; n < 4; ++n)
                acc[m][n] = __builtin_amdgcn_mfma_f32_16x16x32_bf16(
                    a[m], b[n], acc[m][n], 0, 0, 0);
        __builtin_amdgcn_s_barrier();
        cur ^= 1;
    }
#undef STAGE

    const int cl = lane & 15, rq = lane >> 4;
#pragma unroll
    for (int n = 0; n < 4; ++n) {
        int col = colBase + wn * 64 + n * 16 + cl;
        float bv = bias[col];
#pragma unroll
        for (int m = 0; m < 4; ++m) {
            int r0o = rowBase + wm * 64 + m * 16 + rq * 4;
#pragma unroll
            for (int j = 0; j < 4; ++j)
                out[(size_t)(r0o + j) * DOUT + col] = acc[m][n][j] + bv;
        }
    }
}

// ---------------------------------------------------------------------------
extern "C" void kernel_launch(void* const* d_in, const int* in_sizes, int n_in,
                              void* d_out, int out_size, void* d_ws, size_t ws_size,
                              hipStream_t stream) {
    const float* X    = (const float*)d_in[0];   // (B, N, DIN)
    const int*   E    = (const int*)d_in[1];     // (B, 2, NEDGE) int32
    const float* W    = (const float*)d_in[2];   // (DOUT, KDIM)
    const float* bias = (const float*)d_in[3];   // (DOUT,)
    float* out = (float*)d_out;                  // (B, N, DOUT)

    char* ws = (char*)d_ws;
    ushort* Xbf = (ushort*)ws;                                  // 16.78 MB
    ushort* Gbf = Xbf + (size_t)BATCH * NNODE * DIN;            // 16.78 MB
    ushort* Wbf = Gbf + (size_t)BATCH * NNODE * DIN;            // 256 KB
    int* counts = (int*)(Wbf + (size_t)DOUT * KDIM);            // 128 KB
    int* cursor = counts + BATCH * NNODE;                       // 128 KB
    int* srcIdx = cursor + BATCH * NNODE;                       // 4 MB

    // full CSR build (16 blocks, LDS-only atomics) + convert X + convert W
    prep_csr_kernel<<<1056, 1024, 0, stream>>>(
        X, W, E, counts, cursor, srcIdx, Xbf, Wbf);

    aggregate_kernel<<<(BATCH * NNODE) / 4, 256, 0, stream>>>(
        Xbf, srcIdx, cursor, counts, Gbf);

    dim3 ggrid(512);
    gemm_kernel<<<ggrid, 256, 0, stream>>>(Xbf, Gbf, Wbf, bias, out);
}

// Round 7
// 75.866 us; speedup vs baseline: 1.5803x; 1.5803x over previous
//
#include <hip/hip_runtime.h>
#include <hip/hip_bf16.h>

#define BATCH 16
#define NNODE 2048
#define NEDGE 65536
#define DIN   256
#define DOUT  256
#define KDIM  512   // 2*DIN
#define SUB   16            // sub-blocks per batch
#define ESUB  (NEDGE/SUB)   // 4096 edges per sub-block

typedef __attribute__((ext_vector_type(8))) short short8;
typedef __attribute__((ext_vector_type(8))) ushort ushort8;
typedef __attribute__((ext_vector_type(4))) float f32x4;

__device__ __forceinline__ ushort f2bf(float f) {
    union { float f; unsigned u; } v; v.f = f;
    unsigned u = v.u;
    unsigned r = (u + 0x7fffu + ((u >> 16) & 1u)) >> 16;  // RNE
    return (ushort)r;
}
__device__ __forceinline__ float bf2f(ushort h) {
    union { unsigned u; float f; } v; v.u = ((unsigned)h) << 16;
    return v.f;
}

#define ASYNC_COPY16(gsrc, ldst) \
    __builtin_amdgcn_global_load_lds((const __attribute__((address_space(1))) void*)(gsrc), \
                                     (__attribute__((address_space(3))) void*)(ldst), 16, 0, 0)

// ---------------------------------------------------------------------------
// prep (4416 blocks x 256 thr):
//   [0,256):     partial histograms — block (b = bid&15, sub = bid>>4) counts
//                its 4K edges into a private LDS hist, plain-writes to
//                partial[b][sub][*]. Only ~4K LDS atomics per block, spread
//                over 256 CUs (round-6 lesson: LDS atomic tput is per-CU).
//   [256,4352):  convert X fp32->bf16 (8 elems/thread)
//   [4352,4416): convert W fp32->bf16
// ---------------------------------------------------------------------------
__global__ __launch_bounds__(256) void prep_kernel(
        const float* __restrict__ X, const float* __restrict__ W,
        const int* __restrict__ E,
        int* __restrict__ partial,
        ushort* __restrict__ Xbf, ushort* __restrict__ Wbf) {
    int bid = blockIdx.x;
    int t = threadIdx.x;
    if (bid < 256) {
        __shared__ int hist[NNODE];
        int b = bid & 15, sub = bid >> 4;
#pragma unroll
        for (int j = 0; j < 8; ++j) hist[t + j * 256] = 0;
        __syncthreads();
        const int4* dsts = reinterpret_cast<const int4*>(
            E + (size_t)b * 2 * NEDGE + NEDGE + sub * ESUB);
#pragma unroll
        for (int j = 0; j < 4; ++j) {
            int4 d = dsts[j * 256 + t];
            atomicAdd(&hist[d.x], 1);
            atomicAdd(&hist[d.y], 1);
            atomicAdd(&hist[d.z], 1);
            atomicAdd(&hist[d.w], 1);
        }
        __syncthreads();
        int* pb = partial + ((size_t)b * SUB + sub) * NNODE;
#pragma unroll
        for (int j = 0; j < 8; ++j) pb[t + j * 256] = hist[t + j * 256];
    } else if (bid < 4352) {
        size_t i = (size_t)(bid - 256) * 256 + t;
        const float4* p = reinterpret_cast<const float4*>(X + i * 8);
        float4 u = p[0], v = p[1];
        ushort4 o0 = { f2bf(u.x), f2bf(u.y), f2bf(u.z), f2bf(u.w) };
        ushort4 o1 = { f2bf(v.x), f2bf(v.y), f2bf(v.z), f2bf(v.w) };
        *reinterpret_cast<ushort4*>(Xbf + i * 8)     = o0;
        *reinterpret_cast<ushort4*>(Xbf + i * 8 + 4) = o1;
    } else {
        size_t i = (size_t)(bid - 4352) * 256 + t;
        const float4* p = reinterpret_cast<const float4*>(W + i * 8);
        float4 u = p[0], v = p[1];
        ushort4 o0 = { f2bf(u.x), f2bf(u.y), f2bf(u.z), f2bf(u.w) };
        ushort4 o1 = { f2bf(v.x), f2bf(v.y), f2bf(v.z), f2bf(v.w) };
        *reinterpret_cast<ushort4*>(Wbf + i * 8)     = o0;
        *reinterpret_cast<ushort4*>(Wbf + i * 8 + 4) = o1;
    }
}

// ---------------------------------------------------------------------------
// scan (16 blocks x 256 thr, one per batch): sum the 16 partials -> counts,
// exclusive node-scan -> cursor (start offsets), and per-sub prefix ->
// subStart[b][sub][n] (each fill sub-block's private write window).
// ---------------------------------------------------------------------------
__global__ __launch_bounds__(256) void scan_kernel(
        const int* __restrict__ partial,
        int* __restrict__ counts, int* __restrict__ cursor,
        int* __restrict__ subStart) {
    __shared__ int tsum[256];
    int b = blockIdx.x;
    int t = threadIdx.x;
    const int* pb = partial + (size_t)b * SUB * NNODE;
    int tot[8] = {};
    for (int k = 0; k < SUB; ++k) {
        const int4* p = reinterpret_cast<const int4*>(pb + k * NNODE + t * 8);
        int4 a = p[0], c = p[1];
        tot[0] += a.x; tot[1] += a.y; tot[2] += a.z; tot[3] += a.w;
        tot[4] += c.x; tot[5] += c.y; tot[6] += c.z; tot[7] += c.w;
    }
    int s = 0;
#pragma unroll
    for (int j = 0; j < 8; ++j) s += tot[j];
    tsum[t] = s;
    __syncthreads();
    for (int off = 1; off < 256; off <<= 1) {
        int v = (t >= off) ? tsum[t - off] : 0;
        __syncthreads();
        tsum[t] += v;
        __syncthreads();
    }
    int run = (t == 0) ? 0 : tsum[t - 1];
    int base = b * NNODE + t * 8;
    int cur[8];
#pragma unroll
    for (int j = 0; j < 8; ++j) {
        counts[base + j] = tot[j];
        cursor[base + j] = run;
        cur[j] = run;
        run += tot[j];
    }
    int* sb = subStart + (size_t)b * SUB * NNODE;
    for (int k = 0; k < SUB; ++k) {
        const int4* p = reinterpret_cast<const int4*>(pb + k * NNODE + t * 8);
        int4 a = p[0], c = p[1];
        int4 o0 = { cur[0], cur[1], cur[2], cur[3] };
        int4 o1 = { cur[4], cur[5], cur[6], cur[7] };
        *reinterpret_cast<int4*>(sb + k * NNODE + t * 8)     = o0;
        *reinterpret_cast<int4*>(sb + k * NNODE + t * 8 + 4) = o1;
        cur[0] += a.x; cur[1] += a.y; cur[2] += a.z; cur[3] += a.w;
        cur[4] += c.x; cur[5] += c.y; cur[6] += c.z; cur[7] += c.w;
    }
}

// ---------------------------------------------------------------------------
// fill (256 blocks x 256 thr): block (b, sub) scatters its 4K edges into its
// pre-reserved slots via an LDS cursor seeded from subStart. No global
// atomics. srcIdx region per batch is 256KB -> XCD-local (b = bid&15).
// ---------------------------------------------------------------------------
__global__ __launch_bounds__(256) void fill_kernel(
        const int* __restrict__ E,
        const int* __restrict__ subStart,
        int* __restrict__ srcIdx) {
    __shared__ int cur[NNODE];
    int bid = blockIdx.x;
    int t = threadIdx.x;
    int b = bid & 15, sub = bid >> 4;
    const int* ss = subStart + ((size_t)b * SUB + sub) * NNODE;
#pragma unroll
    for (int j = 0; j < 8; ++j) cur[t + j * 256] = ss[t + j * 256];
    __syncthreads();
    const int* eb = E + (size_t)b * 2 * NEDGE;
    const int4* srcs = reinterpret_cast<const int4*>(eb + sub * ESUB);
    const int4* dsts = reinterpret_cast<const int4*>(eb + NEDGE + sub * ESUB);
    int* sb = srcIdx + (size_t)b * NEDGE;
#pragma unroll
    for (int j = 0; j < 4; ++j) {
        int4 s = srcs[j * 256 + t];
        int4 d = dsts[j * 256 + t];
        sb[atomicAdd(&cur[d.x], 1)] = s.x;
        sb[atomicAdd(&cur[d.y], 1)] = s.y;
        sb[atomicAdd(&cur[d.z], 1)] = s.z;
        sb[atomicAdd(&cur[d.w], 1)] = s.w;
    }
}

// ---------------------------------------------------------------------------
// pull-style neighbor mean, bf16 features, fp32 accumulate. One wave per
// node; half-wave per edge; lane owns 8 features (16B loads); 16-edge unroll
// -> 8 independent gathers in flight. XCD swizzle: 2 batches per XCD.
// cursor holds START offsets.
// ---------------------------------------------------------------------------
__global__ __launch_bounds__(256) void aggregate_kernel(
        const ushort* __restrict__ Xbf,
        const int* __restrict__ srcIdx,
        const int* __restrict__ cursor,
        const int* __restrict__ counts,
        ushort* __restrict__ Gbf) {
    int bid = blockIdx.x;                     // 8192 blocks
    int blk = (bid & 7) * 1024 + (bid >> 3);  // XCD-contiguous remap (bijective)
    int wave = threadIdx.x >> 6;
    int lane = threadIdx.x & 63;
    int half = lane >> 5;                     // 0: even edges, 1: odd edges
    int f0 = (lane & 31) * 8;                 // 8 features per lane
    int node = blk * 4 + wave;                // 0 .. B*N-1
    int b = node >> 11;
    int deg = counts[node];
    int start = cursor[node];
    const ushort* xb = Xbf + (size_t)b * NNODE * DIN;
    const int* sidx = srcIdx + (size_t)b * NEDGE + start;

    float acc[8] = {};
    int i = 0;
    for (; i + 16 <= deg; i += 16) {
        int s[8];
#pragma unroll
        for (int u = 0; u < 8; ++u) s[u] = sidx[i + 2 * u + half];
        ushort8 v[8];
#pragma unroll
        for (int u = 0; u < 8; ++u)
            v[u] = *reinterpret_cast<const ushort8*>(xb + (size_t)s[u] * DIN + f0);
#pragma unroll
        for (int u = 0; u < 8; ++u)
#pragma unroll
            for (int j = 0; j < 8; ++j) acc[j] += bf2f(v[u][j]);
    }
    for (; i + 8 <= deg; i += 8) {
        int s0 = sidx[i + 0 + half], s1 = sidx[i + 2 + half];
        int s2 = sidx[i + 4 + half], s3 = sidx[i + 6 + half];
        ushort8 v0 = *reinterpret_cast<const ushort8*>(xb + (size_t)s0 * DIN + f0);
        ushort8 v1 = *reinterpret_cast<const ushort8*>(xb + (size_t)s1 * DIN + f0);
        ushort8 v2 = *reinterpret_cast<const ushort8*>(xb + (size_t)s2 * DIN + f0);
        ushort8 v3 = *reinterpret_cast<const ushort8*>(xb + (size_t)s3 * DIN + f0);
#pragma unroll
        for (int j = 0; j < 8; ++j)
            acc[j] += (bf2f(v0[j]) + bf2f(v1[j])) + (bf2f(v2[j]) + bf2f(v3[j]));
    }
    for (; i + 2 <= deg; i += 2) {
        int s0 = sidx[i + half];
        ushort8 v0 = *reinterpret_cast<const ushort8*>(xb + (size_t)s0 * DIN + f0);
#pragma unroll
        for (int j = 0; j < 8; ++j) acc[j] += bf2f(v0[j]);
    }
    if (i < deg && half == 0) {
        int s0 = sidx[i];
        ushort8 v0 = *reinterpret_cast<const ushort8*>(xb + (size_t)s0 * DIN + f0);
#pragma unroll
        for (int j = 0; j < 8; ++j) acc[j] += bf2f(v0[j]);
    }
#pragma unroll
    for (int j = 0; j < 8; ++j) acc[j] += __shfl_xor(acc[j], 32, 64);

    if (half == 0) {
        float sc = 1.0f / (float)max(deg, 1);
        ushort8 o;
#pragma unroll
        for (int j = 0; j < 8; ++j) o[j] = f2bf(acc[j] * sc);
        *reinterpret_cast<ushort8*>(Gbf + (size_t)node * DIN + f0) = o;
    }
}

// ---------------------------------------------------------------------------
// bf16 MFMA GEMM, 128x128 tile, BK=32, double-buffered LDS, 2-phase pipeline
// (counted vmcnt, raw s_barrier). XCD-chunked swizzle.
// ---------------------------------------------------------------------------
__global__ __launch_bounds__(256) void gemm_kernel(
        const ushort* __restrict__ Xbf,
        const ushort* __restrict__ Gbf,
        const ushort* __restrict__ Wbf,
        const float* __restrict__ bias,
        float* __restrict__ out) {
    __shared__ ushort As[2][128 * 32];   // [buf][row*32 + k]
    __shared__ ushort Bs[2][128 * 32];
    const int tid = threadIdx.x;
    const int wid = tid >> 6, lane = tid & 63;

    int orig = blockIdx.x;
    int logical = (orig & 7) * 64 + (orig >> 3);
    int bx = logical >> 1;
    int by = logical & 1;
    const int rowBase = bx * 128;
    const int colBase = by * 128;
    const int wm = wid >> 1, wn = wid & 1;

    f32x4 acc[4][4] = {};

    const int lr = lane >> 2;
    const int lk = (lane & 3) * 8;

    const ushort* Arow = Xbf + (size_t)rowBase * DIN;
    const ushort* Grow = Gbf + (size_t)rowBase * DIN;
    const ushort* Brow = Wbf + (size_t)colBase * KDIM;
    const int r0 = wid * 16 + lr;

#define STAGE(k0, buf) do {                                                   \
        const ushort* Ab = ((k0) < DIN) ? (Arow + (k0)) : (Grow + ((k0) - DIN)); \
        const ushort* Bb = Brow + (k0);                                       \
        ASYNC_COPY16(Ab + (size_t)r0 * DIN + lk,          &As[buf][wid * 512]);       \
        ASYNC_COPY16(Ab + (size_t)(r0 + 64) * DIN + lk,   &As[buf][2048 + wid * 512]);\
        ASYNC_COPY16(Bb + (size_t)r0 * KDIM + lk,         &Bs[buf][wid * 512]);       \
        ASYNC_COPY16(Bb + (size_t)(r0 + 64) * KDIM + lk,  &Bs[buf][2048 + wid * 512]);\
    } while (0)

    STAGE(0, 0);
    int cur = 0;
    for (int t = 0; t < 16; ++t) {
        if (t < 15) {
            STAGE((t + 1) * 32, cur ^ 1);
            asm volatile("s_waitcnt vmcnt(4)" ::: "memory");
        } else {
            asm volatile("s_waitcnt vmcnt(0)" ::: "memory");
        }
        __builtin_amdgcn_s_barrier();

        short8 a[4], b[4];
#pragma unroll
        for (int m = 0; m < 4; ++m)
            a[m] = *reinterpret_cast<const short8*>(
                &As[cur][(wm * 64 + m * 16 + (lane & 15)) * 32 + (lane >> 4) * 8]);
#pragma unroll
        for (int n = 0; n < 4; ++n)
            b[n] = *reinterpret_cast<const short8*>(
                &Bs[cur][(wn * 64 + n * 16 + (lane & 15)) * 32 + (lane >> 4) * 8]);
#pragma unroll
        for (int m = 0; m < 4; ++m)
#pragma unroll
            for (int n = 0; n < 4; ++n)
                acc[m][n] = __builtin_amdgcn_mfma_f32_16x16x32_bf16(
                    a[m], b[n], acc[m][n], 0, 0, 0);
        __builtin_amdgcn_s_barrier();
        cur ^= 1;
    }
#undef STAGE

    const int cl = lane & 15, rq = lane >> 4;
#pragma unroll
    for (int n = 0; n < 4; ++n) {
        int col = colBase + wn * 64 + n * 16 + cl;
        float bv = bias[col];
#pragma unroll
        for (int m = 0; m < 4; ++m) {
            int r0o = rowBase + wm * 64 + m * 16 + rq * 4;
#pragma unroll
            for (int j = 0; j < 4; ++j)
                out[(size_t)(r0o + j) * DOUT + col] = acc[m][n][j] + bv;
        }
    }
}

// ---------------------------------------------------------------------------
extern "C" void kernel_launch(void* const* d_in, const int* in_sizes, int n_in,
                              void* d_out, int out_size, void* d_ws, size_t ws_size,
                              hipStream_t stream) {
    const float* X    = (const float*)d_in[0];   // (B, N, DIN)
    const int*   E    = (const int*)d_in[1];     // (B, 2, NEDGE) int32
    const float* W    = (const float*)d_in[2];   // (DOUT, KDIM)
    const float* bias = (const float*)d_in[3];   // (DOUT,)
    float* out = (float*)d_out;                  // (B, N, DOUT)

    char* ws = (char*)d_ws;
    ushort* Xbf  = (ushort*)ws;                                 // 16.78 MB
    ushort* Gbf  = Xbf + (size_t)BATCH * NNODE * DIN;           // 16.78 MB
    ushort* Wbf  = Gbf + (size_t)BATCH * NNODE * DIN;           // 256 KB
    int* counts  = (int*)(Wbf + (size_t)DOUT * KDIM);           // 128 KB
    int* cursor  = counts + BATCH * NNODE;                      // 128 KB
    int* srcIdx  = cursor + BATCH * NNODE;                      // 4 MB
    int* partial = srcIdx + (size_t)BATCH * NEDGE;              // 2 MB
    int* subStart= partial + (size_t)BATCH * SUB * NNODE;       // 2 MB

    // partial hists (256 blocks) + convert X (4096) + convert W (64)
    prep_kernel<<<4416, 256, 0, stream>>>(X, W, E, partial, Xbf, Wbf);

    scan_kernel<<<BATCH, 256, 0, stream>>>(partial, counts, cursor, subStart);

    fill_kernel<<<256, 256, 0, stream>>>(E, subStart, srcIdx);

    aggregate_kernel<<<(BATCH * NNODE) / 4, 256, 0, stream>>>(
        Xbf, srcIdx, cursor, counts, Gbf);

    dim3 ggrid(512);
    gemm_kernel<<<ggrid, 256, 0, stream>>>(Xbf, Gbf, Wbf, bias, out);
}